// Round 17
// baseline (198.053 us; speedup 1.0000x reference)
//
#include <hip/hip_runtime.h>
#include <hip/hip_bf16.h>

#define BB 4
#define HH 8
#define LL 2048
#define DD 64

typedef __attribute__((ext_vector_type(8))) short short8;
typedef __attribute__((ext_vector_type(4))) float floatx4;
typedef unsigned int u32;
typedef unsigned short u16;
typedef unsigned long long u64;

// 1/sqrt(DIM/HEADS) * log2(e); folded into Q at prep time.
#define SM_COEF 0.51006977f

#define WAITV(N) asm volatile("s_waitcnt vmcnt(" #N ")" ::: "memory")
#define LGKM0()  asm volatile("s_waitcnt lgkmcnt(0)" ::: "memory")
#define SCHED0() __builtin_amdgcn_sched_barrier(0)

__device__ __forceinline__ void gld_lds16(const void* g, void* l) {
  __builtin_amdgcn_global_load_lds((const __attribute__((address_space(1))) u32*)g,
                                   (__attribute__((address_space(3))) u32*)l, 16, 0, 0);
}

// ---- K0a: transpose+convert Q,K -> ws[g][b][h][i][d] (bf16); Q pre-scaled by SM_COEF ----
__global__ __launch_bounds__(256) void qk_tr_kernel(const float* __restrict__ x,
                                                    unsigned short* __restrict__ ws) {
  const int b = blockIdx.z;
  const int g = blockIdx.y >> 3;   // 0 = Q, 1 = K
  const int h = blockIdx.y & 7;
  const int tid = threadIdx.x;
  const int i = blockIdx.x * 64 + (tid & 63);
  const int dq = tid >> 6;         // which 16-row d-group
  const float scale = (g == 0) ? SM_COEF : 1.0f;
  const float* src = x + ((size_t)(b * 1536 + g * 512 + h * 64 + dq * 16)) * LL + i;
  float v[16];
#pragma unroll
  for (int k = 0; k < 16; ++k) v[k] = src[(size_t)k * LL];
  __hip_bfloat16 hb[16] __attribute__((aligned(16)));
#pragma unroll
  for (int k = 0; k < 16; ++k) hb[k] = __float2bfloat16(v[k] * scale);
  unsigned short* dst = ws + (size_t)g * ((size_t)BB * HH * LL * DD) +
                        ((size_t)(b * HH + h) * LL + i) * DD + dq * 16;
  *reinterpret_cast<short8*>(dst) = *reinterpret_cast<const short8*>(hb);
  *reinterpret_cast<short8*>(dst + 8) = *reinterpret_cast<const short8*>(hb + 8);
}

// ---- K0b: straight convert V: x[b, 1024+h*64+d, j] -> vt[b][h][d][j] (bf16) ----
__global__ __launch_bounds__(256) void v_cv_kernel(const float* __restrict__ x,
                                                   unsigned short* __restrict__ vt) {
  const size_t idx = ((size_t)blockIdx.x * 256 + threadIdx.x) * 4;  // over B*512*L floats
  const size_t row = idx >> 11;   // b*512 + (h*64+d)
  const int col = (int)(idx & 2047);
  const size_t b = row >> 9;
  const size_t r = row & 511;
  const float4 f = *reinterpret_cast<const float4*>(x + ((b * 1536 + 1024 + r) << 11) + col);
  __hip_bfloat16 hb[4] __attribute__((aligned(8)));
  hb[0] = __float2bfloat16(f.x);
  hb[1] = __float2bfloat16(f.y);
  hb[2] = __float2bfloat16(f.z);
  hb[3] = __float2bfloat16(f.w);
  *reinterpret_cast<u64*>(vt + idx) = *reinterpret_cast<const u64*>(hb);
}

// ---- KA: row sums (exact round-14 version). 512 blocks, 4 waves x 32 i-rows, KVBLK=128. ----
__global__ __launch_bounds__(256, 2) void sums_kernel(const u16* __restrict__ qb,
                                                      const u16* __restrict__ kb,
                                                      float* __restrict__ mneg) {
  __shared__ u16 kbuf[2][8192] __attribute__((aligned(16)));  // 2 x (128 rows x 128B)

  const int wg = blockIdx.x;
  const int lin = (wg & 7) * 64 + (wg >> 3);  // XCD-bijective (512 % 8 == 0)
  const int bh = lin >> 4;
  const int ib = lin & 15;                    // 128-row i-block

  const int tid = threadIdx.x;
  const int wave = tid >> 6, lane = tid & 63;
  const int l15 = lane & 15, g = lane >> 4;
  const int swz = (l15 & 7) << 4;
  const int itile = ib * 128 + wave * 32;

  const u16* qrA = qb + ((size_t)bh * LL + itile + l15) * DD + 8 * g;
  const u16* qrB = qrA + 16 * DD;
  const short8 qa0 = *reinterpret_cast<const short8*>(qrA);
  const short8 qa1 = *reinterpret_cast<const short8*>(qrA + 32);
  const short8 qb0 = *reinterpret_cast<const short8*>(qrB);
  const short8 qb1 = *reinterpret_cast<const short8*>(qrB + 32);
  const u16* ktile = kb + (size_t)bh * LL * DD;

  auto stageK = [&](int bsel, int tidx) {
    const char* src = (const char*)(ktile + (size_t)tidx * 128 * DD);
#pragma unroll
    for (int q = 0; q < 4; ++q) {
      const int o = wave * 4096 + q * 1024 + lane * 16;
      const int row = o >> 7;
      const int so = (o & ~127) | ((o & 127) ^ ((row & 7) << 4));
      gld_lds16(src + so, (char*)(&kbuf[bsel][0]) + wave * 4096 + q * 1024);
    }
  };

  float lsA0 = 0.f, lsA1 = 0.f, lsB0 = 0.f, lsB1 = 0.f;
  stageK(0, 0);
  for (int t = 0; t < 16; ++t) {
    WAITV(0);
    __builtin_amdgcn_s_barrier();
    SCHED0();
    stageK((t + 1) & 1, (t + 1) & 15);  // dummy wrap at t=15
    const char* kbb = (const char*)(&kbuf[t & 1][0]);
#pragma unroll
    for (int nt = 0; nt < 8; ++nt) {
      const char* kr = kbb + (nt * 16 + l15) * 128;
      const short8 kf0 = *reinterpret_cast<const short8*>(kr + ((g * 16) ^ swz));
      const short8 kf1 = *reinterpret_cast<const short8*>(kr + ((64 + g * 16) ^ swz));
      floatx4 accA = {0.f, 0.f, 0.f, 0.f}, accB = {0.f, 0.f, 0.f, 0.f};
      accA = __builtin_amdgcn_mfma_f32_16x16x32_bf16(kf0, qa0, accA, 0, 0, 0);
      accA = __builtin_amdgcn_mfma_f32_16x16x32_bf16(kf1, qa1, accA, 0, 0, 0);
      accB = __builtin_amdgcn_mfma_f32_16x16x32_bf16(kf0, qb0, accB, 0, 0, 0);
      accB = __builtin_amdgcn_mfma_f32_16x16x32_bf16(kf1, qb1, accB, 0, 0, 0);
      if (nt & 1) {
#pragma unroll
        for (int r = 0; r < 4; ++r) {
          lsA1 += __builtin_amdgcn_exp2f(accA[r]);
          lsB1 += __builtin_amdgcn_exp2f(accB[r]);
        }
      } else {
#pragma unroll
        for (int r = 0; r < 4; ++r) {
          lsA0 += __builtin_amdgcn_exp2f(accA[r]);
          lsB0 += __builtin_amdgcn_exp2f(accB[r]);
        }
      }
    }
  }
  float lsA = lsA0 + lsA1, lsB = lsB0 + lsB1;
  lsA += __shfl_xor(lsA, 16, 64);
  lsA += __shfl_xor(lsA, 32, 64);
  lsB += __shfl_xor(lsB, 16, 64);
  lsB += __shfl_xor(lsB, 32, 64);
  if (g == 0) {
    mneg[(size_t)bh * LL + itile + l15] = -__log2f(lsA);
    mneg[(size_t)bh * LL + itile + 16 + l15] = -__log2f(lsB);
  }
}

// ---- KB: write pass, V THROUGH LDS (decoupled VMEM FIFO).
// KVBLK=64, 3-buf x 2-ahead staging of BOTH K and V via global_load_lds.
// VMEM FIFO per iter: stage(t+2).4 (K.2+V.2), P(t).8. The ONLY vmem wait is the
// top-of-loop WAITV(20), which forces exactly stage(t) and leaves P(t-1), P(t-2*)
// flying -> P stores get TWO full iterations of slack; PV reads V from LDS so no
// wait can force a P store early. pls P-tile round-trip gives coalesced
// 4-row x 256B full-line P stores (round 14). LDS = 3*8K(K)+3*8K(V)+16K(pls)=64KB. ----
__global__ __launch_bounds__(256, 2) void mha_write_kernel(const u16* __restrict__ qb,
                                                           const u16* __restrict__ kb,
                                                           const u16* __restrict__ vt,
                                                           const float* __restrict__ mneg,
                                                           float* __restrict__ out) {
  __shared__ u16 kbuf[3][4096] __attribute__((aligned(16)));           // 3 x (64 rows x 128B)
  __shared__ u16 vlds[3][4096] __attribute__((aligned(16)));           // 3 x (64 d-rows x 128B)
  __shared__ unsigned char pls[4][4096] __attribute__((aligned(16)));  // per-wave 32x64 bf16 P

  const int wg = blockIdx.x;
  const int lin = (wg & 7) * 64 + (wg >> 3);  // XCD-bijective (512 % 8 == 0)
  const int bh = lin >> 4;
  const int ib = lin & 15;
  const int b = bh >> 3, h = bh & 7;

  const int tid = threadIdx.x;
  const int wave = tid >> 6, lane = tid & 63;
  const int l15 = lane & 15, g = lane >> 4;
  const int swz = (l15 & 7) << 4;
  const int itile = ib * 128 + wave * 32;

  const u16* qrA = qb + ((size_t)bh * LL + itile + l15) * DD + 8 * g;
  const u16* qrB = qrA + 16 * DD;
  const short8 qa0 = *reinterpret_cast<const short8*>(qrA);
  const short8 qa1 = *reinterpret_cast<const short8*>(qrA + 32);
  const short8 qb0 = *reinterpret_cast<const short8*>(qrB);
  const short8 qb1 = *reinterpret_cast<const short8*>(qrB + 32);
  const u16* ktile = kb + (size_t)bh * LL * DD;   // K [j][d]
  const u16* vbase = vt + (size_t)bh * DD * LL;   // V [d][j]
  const float mnA = mneg[(size_t)bh * LL + itile + l15];
  const float mnB = mneg[(size_t)bh * LL + itile + 16 + l15];

  // stage K rows [j0, j0+64): tile 8KB, wave-split, pre-swizzled source
  auto stageK = [&](int bsel, int tidx) {
    const char* src = (const char*)(ktile + (size_t)tidx * 64 * DD);
#pragma unroll
    for (int q = 0; q < 2; ++q) {
      const int o = wave * 2048 + q * 1024 + lane * 16;
      const int row = o >> 7;
      const int so = (o & ~127) | ((o & 127) ^ ((row & 7) << 4));
      gld_lds16(src + so, (char*)(&kbuf[bsel][0]) + wave * 2048 + q * 1024);
    }
  };
  // stage V cols [j0, j0+64) x all 64 d-rows: row d stride LL*2 bytes in global
  auto stageV = [&](int bsel, int tidx) {
    const char* src = (const char*)vbase + (size_t)tidx * 128;  // j0*2 bytes
#pragma unroll
    for (int q = 0; q < 2; ++q) {
      const int o = wave * 2048 + q * 1024 + lane * 16;
      const int row = o >> 7;                       // d-row 0..63
      const int scol = (o & 127) ^ ((row & 7) << 4);
      gld_lds16(src + (size_t)row * (LL * 2) + scol,
                (char*)(&vlds[bsel][0]) + wave * 2048 + q * 1024);
    }
  };

  floatx4 oaccA[4], oaccB[4];
#pragma unroll
  for (int mt = 0; mt < 4; ++mt) {
    oaccA[mt] = (floatx4){0.f, 0.f, 0.f, 0.f};
    oaccB[mt] = (floatx4){0.f, 0.f, 0.f, 0.f};
  }

  // coalesced-store lane mapping (within this wave's 32 rows)
  const int srow = lane >> 4;          // row-in-group 0..3
  const int scol = (lane & 15) * 4;    // j element 0..60
  float* pbase = out + (size_t)BB * 512 * LL + ((size_t)bh * LL + itile) * LL;
  unsigned char* wb = &pls[wave][0];   // rows 0-15 = set A, 16-31 = set B

  stageK(0, 0); stageV(0, 0);
  stageK(1, 1); stageV(1, 1);
  for (int t = 0; t < 32; ++t) {
    // top wait: force exactly stage(t). Outstanding newer ops:
    // t=0: stage(1).4 -> WAITV(4); t=1: stage(2).4+P(0).8 -> WAITV(12);
    // t>=2: P(t-1).8 + stage(t+1).4 + P(t).8? no -- steady: P(t-2) retired by
    // prior top wait; newer-than-stage(t) = P(t-1).8 + stage(t+1).4 + P(t-0)?
    // -> exactly 20 (P(t-1).8 issued after stage(t+1)? order: stage(t+1) in
    // iter t-1 BEFORE P(t-1) -> newer = P(t-1).8 + stage(t+2).4 + P(t).8 = 20).
    if (t == 0) { WAITV(4); } else if (t == 1) { WAITV(12); } else { WAITV(20); }
    __builtin_amdgcn_s_barrier();
    SCHED0();
    stageK((t + 2) % 3, (t + 2) & 31);   // dummy wrap at tail (targets finished bufs)
    stageV((t + 2) % 3, (t + 2) & 31);
    SCHED0();
    const int j0 = t * 64;
    const char* kbb = (const char*)(&kbuf[t % 3][0]);
    const char* vbb = (const char*)(&vlds[t % 3][0]);

    // QK^T + exp -> bf16 P tile in LDS
#pragma unroll
    for (int nt = 0; nt < 4; ++nt) {
      const char* kr = kbb + (nt * 16 + l15) * 128;
      const short8 kf0 = *reinterpret_cast<const short8*>(kr + ((g * 16) ^ swz));
      const short8 kf1 = *reinterpret_cast<const short8*>(kr + ((64 + g * 16) ^ swz));
      floatx4 accA = {0.f, 0.f, 0.f, 0.f}, accB = {0.f, 0.f, 0.f, 0.f};
      accA = __builtin_amdgcn_mfma_f32_16x16x32_bf16(kf0, qa0, accA, 0, 0, 0);
      accA = __builtin_amdgcn_mfma_f32_16x16x32_bf16(kf1, qa1, accA, 0, 0, 0);
      accB = __builtin_amdgcn_mfma_f32_16x16x32_bf16(kf0, qb0, accB, 0, 0, 0);
      accB = __builtin_amdgcn_mfma_f32_16x16x32_bf16(kf1, qb1, accB, 0, 0, 0);
      __hip_bfloat16 ha[4] __attribute__((aligned(8))), hbv[4] __attribute__((aligned(8)));
#pragma unroll
      for (int r = 0; r < 4; ++r) {
        ha[r]  = __float2bfloat16(__builtin_amdgcn_exp2f(accA[r] + mnA));
        hbv[r] = __float2bfloat16(__builtin_amdgcn_exp2f(accB[r] + mnB));
      }
      *reinterpret_cast<u64*>(wb + l15 * 128 + ((nt * 32 + g * 8) ^ swz)) =
          *reinterpret_cast<const u64*>(ha);
      *reinterpret_cast<u64*>(wb + (16 + l15) * 128 + ((nt * 32 + g * 8) ^ swz)) =
          *reinterpret_cast<const u64*>(hbv);
    }
    LGKM0();       // wave-private LDS: P ds_writes visible (rule 18)
    SCHED0();
    // Coalesced P store pass: 8 x (4 rows x 256B contiguous per instruction)
#pragma unroll
    for (int k = 0; k < 8; ++k) {
      const int row = k * 4 + srow;  // 0..31 (A rows 0-15, B rows 16-31)
      const u64 pk = *reinterpret_cast<const u64*>(
          wb + row * 128 + ((scol * 2) ^ ((row & 7) << 4)));
      const u16* pp = (const u16*)&pk;
      float4 pw;
      pw.x = __uint_as_float((u32)pp[0] << 16);
      pw.y = __uint_as_float((u32)pp[1] << 16);
      pw.z = __uint_as_float((u32)pp[2] << 16);
      pw.w = __uint_as_float((u32)pp[3] << 16);
      *reinterpret_cast<float4*>(pbase + (size_t)row * LL + j0 + scol) = pw;
    }
    // PV: V from LDS (swizzled, conflict-free) -- NO vmem wait needed here.
#pragma unroll
    for (int ks = 0; ks < 2; ++ks) {
      const short8 pbA = *reinterpret_cast<const short8*>(
          wb + l15 * 128 + ((ks * 64 + g * 16) ^ swz));
      const short8 pbB = *reinterpret_cast<const short8*>(
          wb + (16 + l15) * 128 + ((ks * 64 + g * 16) ^ swz));
#pragma unroll
      for (int mt = 0; mt < 4; ++mt) {
        const int vrow = mt * 16 + l15;
        const short8 vv = *reinterpret_cast<const short8*>(
            vbb + vrow * 128 + ((ks * 64 + g * 16) ^ ((vrow & 7) << 4)));
        oaccA[mt] = __builtin_amdgcn_mfma_f32_16x16x32_bf16(vv, pbA, oaccA[mt], 0, 0, 0);
        oaccB[mt] = __builtin_amdgcn_mfma_f32_16x16x32_bf16(vv, pbB, oaccB[mt], 0, 0, 0);
      }
    }
  }

  // O^T C-layout (row = d' = mt*16 + 4g + r, col = i) -> out0 [b][h*64+d][i]
  float* obA = out + (size_t)(b * 512 + h * 64) * LL + itile + l15;
  float* obB = obA + 16;
#pragma unroll
  for (int mt = 0; mt < 4; ++mt) {
#pragma unroll
    for (int r = 0; r < 4; ++r) {
      obA[(size_t)(mt * 16 + 4 * g + r) * LL] = oaccA[mt][r];
      obB[(size_t)(mt * 16 + 4 * g + r) * LL] = oaccB[mt][r];
    }
  }
}

extern "C" void kernel_launch(void* const* d_in, const int* in_sizes, int n_in,
                              void* d_out, int out_size, void* d_ws, size_t ws_size,
                              hipStream_t stream) {
  const float* x = (const float*)d_in[0];
  float* out = (float*)d_out;
  unsigned short* ws = (unsigned short*)d_ws;  // 3 * 4M bf16 = 24 MB + 256 KB mneg
  unsigned short* qbuf = ws;
  unsigned short* kbuf = ws + (size_t)BB * HH * LL * DD;
  unsigned short* vbuf = ws + (size_t)2 * BB * HH * LL * DD;
  float* mneg = (float*)(ws + (size_t)3 * BB * HH * LL * DD);

  qk_tr_kernel<<<dim3(32, 16, 4), 256, 0, stream>>>(x, ws);
  v_cv_kernel<<<dim3(4096), 256, 0, stream>>>(x, vbuf);
  sums_kernel<<<dim3(512), 256, 0, stream>>>(qbuf, kbuf, mneg);
  mha_write_kernel<<<dim3(512), 256, 0, stream>>>(qbuf, kbuf, vbuf, mneg, out);
}

// Round 19
// 166.083 us; speedup vs baseline: 1.1925x; 1.1925x over previous
//
#include <hip/hip_runtime.h>
#include <hip/hip_bf16.h>

#define BB 4
#define HH 8
#define LL 2048
#define DD 64

typedef __attribute__((ext_vector_type(8))) short short8;
typedef __attribute__((ext_vector_type(4))) float floatx4;
typedef unsigned int u32;
typedef unsigned short u16;
typedef unsigned long long u64;

// 1/sqrt(DIM/HEADS) * log2(e); folded into Q at prep time.
#define SM_COEF 0.51006977f

#define WAITV(N) asm volatile("s_waitcnt vmcnt(" #N ")" ::: "memory")
#define LGKM0()  asm volatile("s_waitcnt lgkmcnt(0)" ::: "memory")
#define SCHED0() __builtin_amdgcn_sched_barrier(0)

__device__ __forceinline__ void gld_lds16(const void* g, void* l) {
  __builtin_amdgcn_global_load_lds((const __attribute__((address_space(1))) u32*)g,
                                   (__attribute__((address_space(3))) u32*)l, 16, 0, 0);
}

// ---- K0a: transpose+convert Q,K -> ws[g][b][h][i][d] (bf16); Q pre-scaled by SM_COEF ----
__global__ __launch_bounds__(256) void qk_tr_kernel(const float* __restrict__ x,
                                                    unsigned short* __restrict__ ws) {
  const int b = blockIdx.z;
  const int g = blockIdx.y >> 3;   // 0 = Q, 1 = K
  const int h = blockIdx.y & 7;
  const int tid = threadIdx.x;
  const int i = blockIdx.x * 64 + (tid & 63);
  const int dq = tid >> 6;         // which 16-row d-group
  const float scale = (g == 0) ? SM_COEF : 1.0f;
  const float* src = x + ((size_t)(b * 1536 + g * 512 + h * 64 + dq * 16)) * LL + i;
  float v[16];
#pragma unroll
  for (int k = 0; k < 16; ++k) v[k] = src[(size_t)k * LL];
  __hip_bfloat16 hb[16] __attribute__((aligned(16)));
#pragma unroll
  for (int k = 0; k < 16; ++k) hb[k] = __float2bfloat16(v[k] * scale);
  unsigned short* dst = ws + (size_t)g * ((size_t)BB * HH * LL * DD) +
                        ((size_t)(b * HH + h) * LL + i) * DD + dq * 16;
  *reinterpret_cast<short8*>(dst) = *reinterpret_cast<const short8*>(hb);
  *reinterpret_cast<short8*>(dst + 8) = *reinterpret_cast<const short8*>(hb + 8);
}

// ---- K0b: straight convert V: x[b, 1024+h*64+d, j] -> vt[b][h][d][j] (bf16) ----
__global__ __launch_bounds__(256) void v_cv_kernel(const float* __restrict__ x,
                                                   unsigned short* __restrict__ vt) {
  const size_t idx = ((size_t)blockIdx.x * 256 + threadIdx.x) * 4;  // over B*512*L floats
  const size_t row = idx >> 11;   // b*512 + (h*64+d)
  const int col = (int)(idx & 2047);
  const size_t b = row >> 9;
  const size_t r = row & 511;
  const float4 f = *reinterpret_cast<const float4*>(x + ((b * 1536 + 1024 + r) << 11) + col);
  __hip_bfloat16 hb[4] __attribute__((aligned(8)));
  hb[0] = __float2bfloat16(f.x);
  hb[1] = __float2bfloat16(f.y);
  hb[2] = __float2bfloat16(f.z);
  hb[3] = __float2bfloat16(f.w);
  *reinterpret_cast<u64*>(vt + idx) = *reinterpret_cast<const u64*>(hb);
}

// ---- KA: row sums (exact round-14 version). 512 blocks, 4 waves x 32 i-rows, KVBLK=128. ----
__global__ __launch_bounds__(256, 2) void sums_kernel(const u16* __restrict__ qb,
                                                      const u16* __restrict__ kb,
                                                      float* __restrict__ mneg) {
  __shared__ u16 kbuf[2][8192] __attribute__((aligned(16)));  // 2 x (128 rows x 128B)

  const int wg = blockIdx.x;
  const int lin = (wg & 7) * 64 + (wg >> 3);  // XCD-bijective (512 % 8 == 0)
  const int bh = lin >> 4;
  const int ib = lin & 15;                    // 128-row i-block

  const int tid = threadIdx.x;
  const int wave = tid >> 6, lane = tid & 63;
  const int l15 = lane & 15, g = lane >> 4;
  const int swz = (l15 & 7) << 4;
  const int itile = ib * 128 + wave * 32;

  const u16* qrA = qb + ((size_t)bh * LL + itile + l15) * DD + 8 * g;
  const u16* qrB = qrA + 16 * DD;
  const short8 qa0 = *reinterpret_cast<const short8*>(qrA);
  const short8 qa1 = *reinterpret_cast<const short8*>(qrA + 32);
  const short8 qb0 = *reinterpret_cast<const short8*>(qrB);
  const short8 qb1 = *reinterpret_cast<const short8*>(qrB + 32);
  const u16* ktile = kb + (size_t)bh * LL * DD;

  auto stageK = [&](int bsel, int tidx) {
    const char* src = (const char*)(ktile + (size_t)tidx * 128 * DD);
#pragma unroll
    for (int q = 0; q < 4; ++q) {
      const int o = wave * 4096 + q * 1024 + lane * 16;
      const int row = o >> 7;
      const int so = (o & ~127) | ((o & 127) ^ ((row & 7) << 4));
      gld_lds16(src + so, (char*)(&kbuf[bsel][0]) + wave * 4096 + q * 1024);
    }
  };

  float lsA0 = 0.f, lsA1 = 0.f, lsB0 = 0.f, lsB1 = 0.f;
  stageK(0, 0);
  for (int t = 0; t < 16; ++t) {
    WAITV(0);
    __builtin_amdgcn_s_barrier();
    SCHED0();
    stageK((t + 1) & 1, (t + 1) & 15);  // dummy wrap at t=15
    const char* kbb = (const char*)(&kbuf[t & 1][0]);
#pragma unroll
    for (int nt = 0; nt < 8; ++nt) {
      const char* kr = kbb + (nt * 16 + l15) * 128;
      const short8 kf0 = *reinterpret_cast<const short8*>(kr + ((g * 16) ^ swz));
      const short8 kf1 = *reinterpret_cast<const short8*>(kr + ((64 + g * 16) ^ swz));
      floatx4 accA = {0.f, 0.f, 0.f, 0.f}, accB = {0.f, 0.f, 0.f, 0.f};
      accA = __builtin_amdgcn_mfma_f32_16x16x32_bf16(kf0, qa0, accA, 0, 0, 0);
      accA = __builtin_amdgcn_mfma_f32_16x16x32_bf16(kf1, qa1, accA, 0, 0, 0);
      accB = __builtin_amdgcn_mfma_f32_16x16x32_bf16(kf0, qb0, accB, 0, 0, 0);
      accB = __builtin_amdgcn_mfma_f32_16x16x32_bf16(kf1, qb1, accB, 0, 0, 0);
      if (nt & 1) {
#pragma unroll
        for (int r = 0; r < 4; ++r) {
          lsA1 += __builtin_amdgcn_exp2f(accA[r]);
          lsB1 += __builtin_amdgcn_exp2f(accB[r]);
        }
      } else {
#pragma unroll
        for (int r = 0; r < 4; ++r) {
          lsA0 += __builtin_amdgcn_exp2f(accA[r]);
          lsB0 += __builtin_amdgcn_exp2f(accB[r]);
        }
      }
    }
  }
  float lsA = lsA0 + lsA1, lsB = lsB0 + lsB1;
  lsA += __shfl_xor(lsA, 16, 64);
  lsA += __shfl_xor(lsA, 32, 64);
  lsB += __shfl_xor(lsB, 16, 64);
  lsB += __shfl_xor(lsB, 32, 64);
  if (g == 0) {
    mneg[(size_t)bh * LL + itile + l15] = -__log2f(lsA);
    mneg[(size_t)bh * LL + itile + 16 + l15] = -__log2f(lsB);
  }
}

// ---- KB: write pass (round-14 structure) + NON-TEMPORAL P stores (ext-vector type).
// P (512 MB) is write-once/never-read: nt bypasses L2 line allocation so the
// streamed P does not evict the K/V working set being re-read every iteration.
// Everything else identical to round 14 (best measured, 191 us). ----
__global__ __launch_bounds__(256, 2) void mha_write_kernel(const u16* __restrict__ qb,
                                                           const u16* __restrict__ kb,
                                                           const u16* __restrict__ vt,
                                                           const float* __restrict__ mneg,
                                                           float* __restrict__ out) {
  __shared__ u16 kbuf[2][8192] __attribute__((aligned(16)));           // 2 x (128 rows x 128B)
  __shared__ unsigned char pls[4][4096] __attribute__((aligned(16)));  // per-wave 32x64 bf16 P

  const int wg = blockIdx.x;
  const int lin = (wg & 7) * 64 + (wg >> 3);  // XCD-bijective (512 % 8 == 0)
  const int bh = lin >> 4;
  const int ib = lin & 15;
  const int b = bh >> 3, h = bh & 7;

  const int tid = threadIdx.x;
  const int wave = tid >> 6, lane = tid & 63;
  const int l15 = lane & 15, g = lane >> 4;
  const int swz = (l15 & 7) << 4;
  const int itile = ib * 128 + wave * 32;

  const u16* qrA = qb + ((size_t)bh * LL + itile + l15) * DD + 8 * g;
  const u16* qrB = qrA + 16 * DD;
  const short8 qa0 = *reinterpret_cast<const short8*>(qrA);
  const short8 qa1 = *reinterpret_cast<const short8*>(qrA + 32);
  const short8 qb0 = *reinterpret_cast<const short8*>(qrB);
  const short8 qb1 = *reinterpret_cast<const short8*>(qrB + 32);
  const u16* ktile = kb + (size_t)bh * LL * DD;   // K [j][d]
  const u16* vbase = vt + (size_t)bh * DD * LL;   // V [d][j]
  const float mnA = mneg[(size_t)bh * LL + itile + l15];
  const float mnB = mneg[(size_t)bh * LL + itile + 16 + l15];

  auto stageK = [&](int bsel, int tidx) {
    const char* src = (const char*)(ktile + (size_t)tidx * 128 * DD);
#pragma unroll
    for (int q = 0; q < 4; ++q) {
      const int o = wave * 4096 + q * 1024 + lane * 16;
      const int row = o >> 7;
      const int so = (o & ~127) | ((o & 127) ^ ((row & 7) << 4));
      gld_lds16(src + so, (char*)(&kbuf[bsel][0]) + wave * 4096 + q * 1024);
    }
  };

  floatx4 oaccA[4], oaccB[4];
#pragma unroll
  for (int mt = 0; mt < 4; ++mt) {
    oaccA[mt] = (floatx4){0.f, 0.f, 0.f, 0.f};
    oaccB[mt] = (floatx4){0.f, 0.f, 0.f, 0.f};
  }

  // coalesced-store lane mapping (within this wave's 32 rows)
  const int srow = lane >> 4;          // row-in-group 0..3
  const int scol = (lane & 15) * 4;    // j element 0..60
  float* pbase = out + (size_t)BB * 512 * LL + ((size_t)bh * LL + itile) * LL;
  unsigned char* wb = &pls[wave][0];   // rows 0-15 = set A, 16-31 = set B

  stageK(0, 0);
  for (int t = 0; t < 16; ++t) {
    if (t == 0) { WAITV(0); } else { WAITV(16); }   // stage(t) done; P(t-1) may fly
    __builtin_amdgcn_s_barrier();
    SCHED0();
    const int j0 = t * 128;
    // V loads for BOTH halves first (oldest in FIFO)
    short8 vf0a[4], vf0b[4], vf1a[4], vf1b[4];
    {
      const u16* vc0 = vbase + (size_t)l15 * LL + j0 + 8 * g;
      const u16* vc1 = vc0 + 64;
#pragma unroll
      for (int mt = 0; mt < 4; ++mt) {
        vf0a[mt] = *reinterpret_cast<const short8*>(vc0 + (size_t)mt * 16 * LL);
        vf0b[mt] = *reinterpret_cast<const short8*>(vc0 + (size_t)mt * 16 * LL + 32);
      }
#pragma unroll
      for (int mt = 0; mt < 4; ++mt) {
        vf1a[mt] = *reinterpret_cast<const short8*>(vc1 + (size_t)mt * 16 * LL);
        vf1b[mt] = *reinterpret_cast<const short8*>(vc1 + (size_t)mt * 16 * LL + 32);
      }
    }
    SCHED0();
    stageK((t + 1) & 1, (t + 1) & 15);   // dummy wrap at t=15
    SCHED0();
    const char* kbb = (const char*)(&kbuf[t & 1][0]);

#pragma unroll
    for (int hf = 0; hf < 2; ++hf) {
      const int jh = j0 + hf * 64;
      // QK^T + exp -> bf16 P tile in LDS (no direct global stores here)
#pragma unroll
      for (int nt = 0; nt < 4; ++nt) {
        const char* kr = kbb + ((hf * 64 + nt * 16) + l15) * 128;
        const short8 kf0 = *reinterpret_cast<const short8*>(kr + ((g * 16) ^ swz));
        const short8 kf1 = *reinterpret_cast<const short8*>(kr + ((64 + g * 16) ^ swz));
        floatx4 accA = {0.f, 0.f, 0.f, 0.f}, accB = {0.f, 0.f, 0.f, 0.f};
        accA = __builtin_amdgcn_mfma_f32_16x16x32_bf16(kf0, qa0, accA, 0, 0, 0);
        accA = __builtin_amdgcn_mfma_f32_16x16x32_bf16(kf1, qa1, accA, 0, 0, 0);
        accB = __builtin_amdgcn_mfma_f32_16x16x32_bf16(kf0, qb0, accB, 0, 0, 0);
        accB = __builtin_amdgcn_mfma_f32_16x16x32_bf16(kf1, qb1, accB, 0, 0, 0);
        __hip_bfloat16 ha[4] __attribute__((aligned(8))), hbv[4] __attribute__((aligned(8)));
#pragma unroll
        for (int r = 0; r < 4; ++r) {
          ha[r]  = __float2bfloat16(__builtin_amdgcn_exp2f(accA[r] + mnA));
          hbv[r] = __float2bfloat16(__builtin_amdgcn_exp2f(accB[r] + mnB));
        }
        *reinterpret_cast<u64*>(wb + l15 * 128 + ((nt * 32 + g * 8) ^ swz)) =
            *reinterpret_cast<const u64*>(ha);
        *reinterpret_cast<u64*>(wb + (16 + l15) * 128 + ((nt * 32 + g * 8) ^ swz)) =
            *reinterpret_cast<const u64*>(hbv);
      }
      LGKM0();       // wave-private LDS: P ds_writes visible (rule 18)
      SCHED0();
      // Coalesced P store pass, NON-TEMPORAL: 8 x (4 rows x 256B full lines)
#pragma unroll
      for (int k = 0; k < 8; ++k) {
        const int row = k * 4 + srow;  // 0..31 (A rows 0-15, B rows 16-31)
        const u64 pk = *reinterpret_cast<const u64*>(
            wb + row * 128 + ((scol * 2) ^ ((row & 7) << 4)));
        const u16* pp = (const u16*)&pk;
        floatx4 pw;
        pw[0] = __uint_as_float((u32)pp[0] << 16);
        pw[1] = __uint_as_float((u32)pp[1] << 16);
        pw[2] = __uint_as_float((u32)pp[2] << 16);
        pw[3] = __uint_as_float((u32)pp[3] << 16);
        __builtin_nontemporal_store(
            pw, reinterpret_cast<floatx4*>(pbase + (size_t)row * LL + jh + scol));
      }
      // pre-PV: force this half's V loads (retires P(t-1) with 1-iter slack)
      WAITV(20);
      SCHED0();
#pragma unroll
      for (int ks = 0; ks < 2; ++ks) {
        const short8 pbA = *reinterpret_cast<const short8*>(
            wb + l15 * 128 + ((ks * 64 + g * 16) ^ swz));
        const short8 pbB = *reinterpret_cast<const short8*>(
            wb + (16 + l15) * 128 + ((ks * 64 + g * 16) ^ swz));
#pragma unroll
        for (int mt = 0; mt < 4; ++mt) {
          const short8 vv = hf == 0 ? (ks == 0 ? vf0a[mt] : vf0b[mt])
                                    : (ks == 0 ? vf1a[mt] : vf1b[mt]);
          oaccA[mt] = __builtin_amdgcn_mfma_f32_16x16x32_bf16(vv, pbA, oaccA[mt], 0, 0, 0);
          oaccB[mt] = __builtin_amdgcn_mfma_f32_16x16x32_bf16(vv, pbB, oaccB[mt], 0, 0, 0);
        }
      }
    }
  }

  // O^T C-layout (row = d' = mt*16 + 4g + r, col = i) -> out0 [b][h*64+d][i]
  float* obA = out + (size_t)(b * 512 + h * 64) * LL + itile + l15;
  float* obB = obA + 16;
#pragma unroll
  for (int mt = 0; mt < 4; ++mt) {
#pragma unroll
    for (int r = 0; r < 4; ++r) {
      obA[(size_t)(mt * 16 + 4 * g + r) * LL] = oaccA[mt][r];
      obB[(size_t)(mt * 16 + 4 * g + r) * LL] = oaccB[mt][r];
    }
  }
}

extern "C" void kernel_launch(void* const* d_in, const int* in_sizes, int n_in,
                              void* d_out, int out_size, void* d_ws, size_t ws_size,
                              hipStream_t stream) {
  const float* x = (const float*)d_in[0];
  float* out = (float*)d_out;
  unsigned short* ws = (unsigned short*)d_ws;  // 3 * 4M bf16 = 24 MB + 256 KB mneg
  unsigned short* qbuf = ws;
  unsigned short* kbuf = ws + (size_t)BB * HH * LL * DD;
  unsigned short* vbuf = ws + (size_t)2 * BB * HH * LL * DD;
  float* mneg = (float*)(ws + (size_t)3 * BB * HH * LL * DD);

  qk_tr_kernel<<<dim3(32, 16, 4), 256, 0, stream>>>(x, ws);
  v_cv_kernel<<<dim3(4096), 256, 0, stream>>>(x, vbuf);
  sums_kernel<<<dim3(512), 256, 0, stream>>>(qbuf, kbuf, mneg);
  mha_write_kernel<<<dim3(512), 256, 0, stream>>>(qbuf, kbuf, vbuf, mneg, out);
}